// Round 2
// baseline (1137.416 us; speedup 1.0000x reference)
//
#include <hip/hip_runtime.h>
#include <hip/hip_bf16.h>
#include <type_traits>

// B=16, S=1024, E=1024, fp32 in/out.
// q/k/v proj -> scores=qk^T/32 -> flat softmax/batch -> attn=w@v -> LN1(+pl)
//   -> h=x@W1 (K-split) -> ff=h@W2 (accumulate) -> LN2(+x)
// Attention path bf16 (attn ~1e-4 scale vs unit residual); FFN split-bf16 hi/lo.
// Workspace budget: 214 MiB + 128 KiB (regions reused across phases).

typedef float  f32x4  __attribute__((ext_vector_type(4)));
typedef unsigned short u16x8 __attribute__((ext_vector_type(8)));
typedef unsigned short u16x4 __attribute__((ext_vector_type(4)));
typedef __bf16 bf16x8 __attribute__((ext_vector_type(8)));

__device__ __forceinline__ unsigned short f2bf(float f) {
  unsigned int u = __float_as_uint(f);
  u += 0x7fffu + ((u >> 16) & 1u);   // RNE
  return (unsigned short)(u >> 16);
}
__device__ __forceinline__ float bf2f(unsigned short h) {
  return __uint_as_float(((unsigned int)h) << 16);
}

template<int SPLIT>
__device__ __forceinline__ void cvt8(const float4& a, const float4& b, u16x8& h, u16x8& l) {
  float f[8] = {a.x, a.y, a.z, a.w, b.x, b.y, b.z, b.w};
#pragma unroll
  for (int i = 0; i < 8; ++i) {
    unsigned short hb = f2bf(f[i]);
    h[i] = hb;
    if constexpr (SPLIT) l[i] = f2bf(f[i] - bf2f(hb));
  }
}

// C[M][N] = scale*(A @ Bt^T) + beta*C, batched over blockIdx.z.
// AM/BM: 0 = bf16 input, 1 = f32 input (bf16-hi only), 2 = f32 input split hi/lo.
// CM: 0 = f32 out (beta supported), 1 = bf16 out.
// 128x128 tile, BK=32, 256 thr = 4 waves (2x2 of 64x64), mfma_f32_16x16x32_bf16.
template<int AM, int BM, int CM>
__global__ __launch_bounds__(256, 2)
void gemm(const void* __restrict__ Av, const void* __restrict__ Bv,
          void* __restrict__ Cv, int M, int N, int K, int lda, int ldb,
          long sA, long sB, long sC, float scale, float beta)
{
  constexpr bool SA = (AM == 2), SB = (BM == 2);
  constexpr int NB = 2 + (SA ? 1 : 0) + (SB ? 1 : 0);
  constexpr int IAL = 2;              // lo(A) buffer index (only if SA)
  constexpr int IBL = SA ? 3 : 2;     // lo(B) buffer index (only if SB)
  __shared__ unsigned short sh[NB][4][128][8];

  const int t    = threadIdx.x;
  const int lane = t & 63;
  const int wave = t >> 6;
  const int wm   = (wave >> 1) << 6;
  const int wn   = (wave & 1) << 6;
  const int bm   = blockIdx.x << 7;
  const int bn   = blockIdx.y << 7;
  const int r_   = t >> 1;            // staged tile row
  const int g_   = t & 1;             // k-chunk pair (g_ and g_+2)

  const unsigned short* A16 = (const unsigned short*)Av + (size_t)blockIdx.z * sA + (size_t)(bm + r_) * lda + (g_ << 3);
  const float*          A32 = (const float*)Av          + (size_t)blockIdx.z * sA + (size_t)(bm + r_) * lda + (g_ << 3);
  const unsigned short* B16 = (const unsigned short*)Bv + (size_t)blockIdx.z * sB + (size_t)(bn + r_) * ldb + (g_ << 3);
  const float*          B32 = (const float*)Bv          + (size_t)blockIdx.z * sB + (size_t)(bn + r_) * ldb + (g_ << 3);

  f32x4 acc[4][4];
#pragma unroll
  for (int mi = 0; mi < 4; ++mi)
#pragma unroll
    for (int ni = 0; ni < 4; ++ni)
      acc[mi][ni] = (f32x4){0.f, 0.f, 0.f, 0.f};

  u16x8 ha0, ha1, hb0, hb1;
  float4 fa0, fa1, fa2, fa3, fb0, fb1, fb2, fb3;

  auto loadAB = [&](int kt) {
    const int ko = kt << 5;
    if constexpr (AM == 0) {
      ha0 = *(const u16x8*)(A16 + ko);
      ha1 = *(const u16x8*)(A16 + ko + 16);
    } else {
      fa0 = *(const float4*)(A32 + ko);      fa1 = *(const float4*)(A32 + ko + 4);
      fa2 = *(const float4*)(A32 + ko + 16); fa3 = *(const float4*)(A32 + ko + 20);
    }
    if constexpr (BM == 0) {
      hb0 = *(const u16x8*)(B16 + ko);
      hb1 = *(const u16x8*)(B16 + ko + 16);
    } else {
      fb0 = *(const float4*)(B32 + ko);      fb1 = *(const float4*)(B32 + ko + 4);
      fb2 = *(const float4*)(B32 + ko + 16); fb3 = *(const float4*)(B32 + ko + 20);
    }
  };
  loadAB(0);

  const int NT = K >> 5;
  const int kg = lane >> 4;
  const int lr = lane & 15;

  for (int kt = 0; kt < NT; ++kt) {
    __syncthreads();   // frag reads of previous tile complete
    if constexpr (AM == 0) {
      *(u16x8*)&sh[0][g_][r_][0]     = ha0;
      *(u16x8*)&sh[0][g_ + 2][r_][0] = ha1;
    } else {
      u16x8 h, l;
      cvt8<SA>(fa0, fa1, h, l);
      *(u16x8*)&sh[0][g_][r_][0] = h;     if constexpr (SA) *(u16x8*)&sh[IAL][g_][r_][0] = l;
      cvt8<SA>(fa2, fa3, h, l);
      *(u16x8*)&sh[0][g_ + 2][r_][0] = h; if constexpr (SA) *(u16x8*)&sh[IAL][g_ + 2][r_][0] = l;
    }
    if constexpr (BM == 0) {
      *(u16x8*)&sh[1][g_][r_][0]     = hb0;
      *(u16x8*)&sh[1][g_ + 2][r_][0] = hb1;
    } else {
      u16x8 h, l;
      cvt8<SB>(fb0, fb1, h, l);
      *(u16x8*)&sh[1][g_][r_][0] = h;     if constexpr (SB) *(u16x8*)&sh[IBL][g_][r_][0] = l;
      cvt8<SB>(fb2, fb3, h, l);
      *(u16x8*)&sh[1][g_ + 2][r_][0] = h; if constexpr (SB) *(u16x8*)&sh[IBL][g_ + 2][r_][0] = l;
    }
    __syncthreads();

    if (kt + 1 < NT) loadAB(kt + 1);   // overlap next global loads with MFMA

    u16x8 va_[4], vb_[4], val_[4], vbl_[4];
#pragma unroll
    for (int mi = 0; mi < 4; ++mi) {
      va_[mi] = *(const u16x8*)&sh[0][kg][wm + (mi << 4) + lr][0];
      if constexpr (SA) val_[mi] = *(const u16x8*)&sh[IAL][kg][wm + (mi << 4) + lr][0];
    }
#pragma unroll
    for (int ni = 0; ni < 4; ++ni) {
      vb_[ni] = *(const u16x8*)&sh[1][kg][wn + (ni << 4) + lr][0];
      if constexpr (SB) vbl_[ni] = *(const u16x8*)&sh[IBL][kg][wn + (ni << 4) + lr][0];
    }
#pragma unroll
    for (int mi = 0; mi < 4; ++mi)
#pragma unroll
      for (int ni = 0; ni < 4; ++ni) {
        acc[mi][ni] = __builtin_amdgcn_mfma_f32_16x16x32_bf16(
            __builtin_bit_cast(bf16x8, va_[mi]), __builtin_bit_cast(bf16x8, vb_[ni]),
            acc[mi][ni], 0, 0, 0);
        if constexpr (SB)
          acc[mi][ni] = __builtin_amdgcn_mfma_f32_16x16x32_bf16(
              __builtin_bit_cast(bf16x8, va_[mi]), __builtin_bit_cast(bf16x8, vbl_[ni]),
              acc[mi][ni], 0, 0, 0);
        if constexpr (SA)
          acc[mi][ni] = __builtin_amdgcn_mfma_f32_16x16x32_bf16(
              __builtin_bit_cast(bf16x8, val_[mi]), __builtin_bit_cast(bf16x8, vb_[ni]),
              acc[mi][ni], 0, 0, 0);
      }
  }

  // D lane map: col=lane&15, row=(lane>>4)*4+i  [m89-verified]
  const size_t cbase = (size_t)blockIdx.z * sC;
#pragma unroll
  for (int mi = 0; mi < 4; ++mi)
#pragma unroll
    for (int ni = 0; ni < 4; ++ni) {
      const int row0 = bm + wm + (mi << 4) + ((lane >> 4) << 2);
      const int col  = bn + wn + (ni << 4) + lr;
#pragma unroll
      for (int i = 0; i < 4; ++i) {
        float val = acc[mi][ni][i] * scale;
        const size_t idx = cbase + (size_t)(row0 + i) * N + col;
        if constexpr (CM == 0) {
          float* C = (float*)Cv;
          if (beta != 0.f) val += beta * C[idx];
          C[idx] = val;
        } else {
          ((unsigned short*)Cv)[idx] = f2bf(val);
        }
      }
    }
}

// out[c][r] = in[r][c], fp32<->bf16 per template, batched via blockIdx.z. block (32,8).
template<typename IT, typename OT>
__global__ __launch_bounds__(256)
void transpose_k(const IT* __restrict__ in, OT* __restrict__ out,
                 int R, int C, long sIn, long sOut)
{
  __shared__ float tile[32][33];
  in  += (size_t)blockIdx.z * sIn;
  out += (size_t)blockIdx.z * sOut;
  const int tx = threadIdx.x, ty = threadIdx.y;
  const int c0 = blockIdx.x << 5, r0 = blockIdx.y << 5;
#pragma unroll
  for (int i = 0; i < 4; ++i) {
    int r = ty + (i << 3);
    float v;
    if constexpr (std::is_same_v<IT, unsigned short>)
      v = bf2f(in[(size_t)(r0 + r) * C + c0 + tx]);
    else
      v = in[(size_t)(r0 + r) * C + c0 + tx];
    tile[r][tx] = v;
  }
  __syncthreads();
#pragma unroll
  for (int i = 0; i < 4; ++i) {
    int r = ty + (i << 3);
    float v = tile[tx][r];
    if constexpr (std::is_same_v<OT, unsigned short>)
      out[(size_t)(c0 + r) * R + r0 + tx] = f2bf(v);
    else
      out[(size_t)(c0 + r) * R + r0 + tx] = v;
  }
}

// flat softmax over 1M elems/batch: per-4096-chunk (max, sum e^(x-max)).
__global__ __launch_bounds__(256)
void softmax_pass1(const float* __restrict__ sc, float2* __restrict__ part)
{
  const int b = blockIdx.y;
  const float* p = sc + ((size_t)b << 20) + ((size_t)blockIdx.x << 12);
  const int t = threadIdx.x;
  float v[16];
#pragma unroll
  for (int i = 0; i < 4; ++i) {
    float4 f = *(const float4*)(p + (t << 2) + (i << 10));
    v[i * 4 + 0] = f.x; v[i * 4 + 1] = f.y; v[i * 4 + 2] = f.z; v[i * 4 + 3] = f.w;
  }
  float m = v[0];
#pragma unroll
  for (int i = 1; i < 16; ++i) m = fmaxf(m, v[i]);
  for (int off = 32; off; off >>= 1) m = fmaxf(m, __shfl_down(m, off));
  __shared__ float red[8];
  if ((t & 63) == 0) red[t >> 6] = m;
  __syncthreads();
  m = fmaxf(fmaxf(red[0], red[1]), fmaxf(red[2], red[3]));
  float s = 0.f;
#pragma unroll
  for (int i = 0; i < 16; ++i) s += __expf(v[i] - m);
  for (int off = 32; off; off >>= 1) s += __shfl_down(s, off);
  if ((t & 63) == 0) red[4 + (t >> 6)] = s;
  __syncthreads();
  if (t == 0) part[(b << 8) + blockIdx.x] = make_float2(m, red[4] + red[5] + red[6] + red[7]);
}

__global__ __launch_bounds__(256)
void softmax_pass2(const float2* __restrict__ part, float2* __restrict__ bstats)
{
  const int b = blockIdx.x, t = threadIdx.x;
  float2 pr = part[(b << 8) + t];
  float m = pr.x;
  for (int off = 32; off; off >>= 1) m = fmaxf(m, __shfl_down(m, off));
  __shared__ float red[8];
  if ((t & 63) == 0) red[t >> 6] = m;
  __syncthreads();
  m = fmaxf(fmaxf(red[0], red[1]), fmaxf(red[2], red[3]));
  float s = pr.y * __expf(pr.x - m);
  for (int off = 32; off; off >>= 1) s += __shfl_down(s, off);
  __shared__ float red2[4];
  if ((t & 63) == 0) red2[t >> 6] = s;
  __syncthreads();
  if (t == 0) bstats[b] = make_float2(m, 1.f / (red2[0] + red2[1] + red2[2] + red2[3]));
}

// normalize + write bf16 weights
__global__ __launch_bounds__(256)
void softmax_pass3(const float* __restrict__ sc, unsigned short* __restrict__ wb,
                   const float2* __restrict__ bst)
{
  const int b = blockIdx.y;
  const float2 st = bst[b];
  const size_t off = ((size_t)b << 20) + ((size_t)blockIdx.x << 12) + ((size_t)threadIdx.x << 2);
  const float* p = sc + off;
  unsigned short* o = wb + off;
#pragma unroll
  for (int i = 0; i < 4; ++i) {
    float4 f = *(const float4*)(p + (i << 10));
    u16x4 u;
    u[0] = f2bf(__expf(f.x - st.x) * st.y);
    u[1] = f2bf(__expf(f.y - st.x) * st.y);
    u[2] = f2bf(__expf(f.z - st.x) * st.y);
    u[3] = f2bf(__expf(f.w - st.x) * st.y);
    *(u16x4*)(o + (i << 10)) = u;
  }
}

// out = LN(a + res) * g + b ; one block per 1024-elem row. a may be bf16.
template<typename TA>
__global__ __launch_bounds__(256)
void ln_fused(const TA* __restrict__ a, const float* __restrict__ res,
              const float* __restrict__ g, const float* __restrict__ bb,
              float* __restrict__ out)
{
  const size_t base = (size_t)blockIdx.x << 10;
  const int t = threadIdx.x;
  float x0, x1, x2, x3;
  if constexpr (std::is_same_v<TA, unsigned short>) {
    u16x4 va = *(const u16x4*)(a + base + (t << 2));
    x0 = bf2f(va[0]); x1 = bf2f(va[1]); x2 = bf2f(va[2]); x3 = bf2f(va[3]);
  } else {
    float4 va = *(const float4*)(a + base + (t << 2));
    x0 = va.x; x1 = va.y; x2 = va.z; x3 = va.w;
  }
  float4 vr = *(const float4*)(res + base + (t << 2));
  x0 += vr.x; x1 += vr.y; x2 += vr.z; x3 += vr.w;
  float s = x0 + x1 + x2 + x3;
  float q = x0 * x0 + x1 * x1 + x2 * x2 + x3 * x3;
  for (int off = 32; off; off >>= 1) { s += __shfl_down(s, off); q += __shfl_down(q, off); }
  __shared__ float red[8];
  if ((t & 63) == 0) { red[t >> 6] = s; red[4 + (t >> 6)] = q; }
  __syncthreads();
  float S = red[0] + red[1] + red[2] + red[3];
  float Q = red[4] + red[5] + red[6] + red[7];
  float mu   = S * 0.0009765625f;
  float rstd = rsqrtf(Q * 0.0009765625f - mu * mu + 1e-5f);
  float4 vg = *(const float4*)(g + (t << 2));
  float4 vb = *(const float4*)(bb + (t << 2));
  float4 o;
  o.x = (x0 - mu) * rstd * vg.x + vb.x;
  o.y = (x1 - mu) * rstd * vg.y + vb.y;
  o.z = (x2 - mu) * rstd * vg.z + vb.z;
  o.w = (x3 - mu) * rstd * vg.w + vb.w;
  *(float4*)(out + base + (t << 2)) = o;
}

extern "C" void kernel_launch(void* const* d_in, const int* in_sizes, int n_in,
                              void* d_out, int out_size, void* d_ws, size_t ws_size,
                              hipStream_t stream)
{
  const float* pl  = (const float*)d_in[0];
  const float* sam = (const float*)d_in[1];
  const float* Wq  = (const float*)d_in[2];
  const float* Wk  = (const float*)d_in[3];
  const float* Wv  = (const float*)d_in[4];
  const float* g1  = (const float*)d_in[5];
  const float* b1  = (const float*)d_in[6];
  const float* W1  = (const float*)d_in[7];
  const float* W2  = (const float*)d_in[8];
  const float* g2  = (const float*)d_in[9];
  const float* b2  = (const float*)d_in[10];

  // ---- workspace layout (byte offsets), total 214 MiB + 128 KiB ----
  char* wsb = (char*)d_ws;
  const size_t MB = 1ull << 20;
  unsigned short* WqTb = (unsigned short*)(wsb + 0 * MB);    // 2 MiB  bf16 [1024][1024]
  unsigned short* WkTb = (unsigned short*)(wsb + 2 * MB);    // 2 MiB
  unsigned short* WvTb = (unsigned short*)(wsb + 4 * MB);    // 2 MiB
  float*  W1T  = (float*)(wsb + 6 * MB);                     // 8 MiB  f32 [2048][1024]
  float*  W2T  = (float*)(wsb + 14 * MB);                    // 8 MiB  f32 [1024][2048]
  unsigned short* qb   = (unsigned short*)(wsb + 22 * MB);   // A region 32 MiB (later attnb)
  unsigned short* kb   = (unsigned short*)(wsb + 54 * MB);   // B region 32 MiB (later w)
  unsigned short* vb   = (unsigned short*)(wsb + 86 * MB);   // C region 32 MiB
  unsigned short* vTb  = (unsigned short*)(wsb + 118 * MB);  // D region 32 MiB
  float*  hbuf  = (float*)(wsb + 86 * MB);                   // C∪D 64 MiB (after v dead)
  float*  ffbuf = (float*)(wsb + 22 * MB);                   // A∪B 64 MiB (after attn/w dead)
  float*  sc    = (float*)(wsb + 150 * MB);                  // E region 64 MiB (later x)
  float*  xbuf  = sc;
  float2* part  = (float2*)(wsb + 214 * MB);                 // 32 KiB
  float2* bst   = (float2*)(wsb + 214 * MB + 65536);
  unsigned short* attnb = qb;
  unsigned short* wb_   = kb;

  const long M1 = 1 << 20;
  dim3 tb(32, 8);

  // weight transposes (Wq/Wk/Wv -> bf16; W1/W2 -> f32 for split path)
  transpose_k<float, unsigned short><<<dim3(32, 32, 1), tb, 0, stream>>>(Wq, WqTb, 1024, 1024, 0, 0);
  transpose_k<float, unsigned short><<<dim3(32, 32, 1), tb, 0, stream>>>(Wk, WkTb, 1024, 1024, 0, 0);
  transpose_k<float, unsigned short><<<dim3(32, 32, 1), tb, 0, stream>>>(Wv, WvTb, 1024, 1024, 0, 0);
  transpose_k<float, float><<<dim3(64, 32, 1), tb, 0, stream>>>(W1, W1T, 1024, 2048, 0, 0);
  transpose_k<float, float><<<dim3(32, 64, 1), tb, 0, stream>>>(W2, W2T, 2048, 1024, 0, 0);

  // projections: f32 A, bf16 B, bf16 out
  gemm<1, 0, 1><<<dim3(128, 8, 1), 256, 0, stream>>>(pl,  WqTb, qb, 16384, 1024, 1024, 1024, 1024, 0, 0, 0, 1.f, 0.f);
  gemm<1, 0, 1><<<dim3(128, 8, 1), 256, 0, stream>>>(sam, WkTb, kb, 16384, 1024, 1024, 1024, 1024, 0, 0, 0, 1.f, 0.f);
  gemm<1, 0, 1><<<dim3(128, 8, 1), 256, 0, stream>>>(sam, WvTb, vb, 16384, 1024, 1024, 1024, 1024, 0, 0, 0, 1.f, 0.f);

  transpose_k<unsigned short, unsigned short><<<dim3(32, 32, 16), tb, 0, stream>>>(vb, vTb, 1024, 1024, M1, M1);

  // scores = q @ k^T / 32 (bf16 in, f32 out, batched)
  gemm<0, 0, 0><<<dim3(8, 8, 16), 256, 0, stream>>>(qb, kb, sc, 1024, 1024, 1024, 1024, 1024, M1, M1, M1, 0.03125f, 0.f);

  softmax_pass1<<<dim3(256, 16, 1), 256, 0, stream>>>(sc, part);
  softmax_pass2<<<16, 256, 0, stream>>>(part, bst);
  softmax_pass3<<<dim3(256, 16, 1), 256, 0, stream>>>(sc, wb_, bst);

  // attn = w @ v  (bf16 in, bf16 out; B^T = vT)
  gemm<0, 0, 1><<<dim3(8, 8, 16), 256, 0, stream>>>(wb_, vTb, attnb, 1024, 1024, 1024, 1024, 1024, M1, M1, M1, 1.f, 0.f);

  ln_fused<unsigned short><<<16384, 256, 0, stream>>>(attnb, pl, g1, b1, xbuf);

  // FFN, K-split into 2 halves; split-bf16 hi/lo (3 MFMAs) for near-fp32 accuracy
  gemm<2, 2, 0><<<dim3(128, 8, 1), 256, 0, stream>>>(xbuf, W1T,              hbuf,  16384, 1024, 1024, 1024, 1024, 0, 0, 0, 1.f, 0.f);
  gemm<2, 2, 0><<<dim3(128, 8, 1), 256, 0, stream>>>(hbuf, W2T,              ffbuf, 16384, 1024, 1024, 1024, 2048, 0, 0, 0, 1.f, 0.f);
  gemm<2, 2, 0><<<dim3(128, 8, 1), 256, 0, stream>>>(xbuf, W1T + (1024*1024), hbuf,  16384, 1024, 1024, 1024, 1024, 0, 0, 0, 1.f, 0.f);
  gemm<2, 2, 0><<<dim3(128, 8, 1), 256, 0, stream>>>(hbuf, W2T + 1024,        ffbuf, 16384, 1024, 1024, 1024, 2048, 0, 0, 0, 1.f, 1.f);

  ln_fused<float><<<16384, 256, 0, stream>>>(ffbuf, xbuf, g2, b2, (float*)d_out);
}

// Round 8
// 1023.540 us; speedup vs baseline: 1.1113x; 1.1113x over previous
//
#include <hip/hip_runtime.h>

// B=16, S=1024, E=1024, fp32 in/out.
// q/k/v proj (bf16 MFMA) -> scores=qk^T/32 -> flat softmax/batch -> attn=w@v
//   -> LN1(+pl) -> FFN in fp16 hi/lo split (2-term, ~2^-12 rel) -> LN2(+x)
// GEMMs: 128x128 tile, BK=32, 4 waves, pure 16-bit operands.
// Staging: reg-staged global u16x8 loads -> ds_write_b128 (replay-proven
// transport; global_load_lds variant raced on warm-clock graph replays).

typedef float  f32x4 __attribute__((ext_vector_type(4)));
typedef unsigned short u16;
typedef unsigned short u16x8 __attribute__((ext_vector_type(8)));
typedef unsigned short u16x4 __attribute__((ext_vector_type(4)));
typedef __bf16 bf16x8 __attribute__((ext_vector_type(8)));
typedef _Float16 f16x8 __attribute__((ext_vector_type(8)));

__device__ __forceinline__ u16 f2bf(float f) {
  unsigned int u = __float_as_uint(f);
  u += 0x7fffu + ((u >> 16) & 1u);   // RNE
  return (u16)(u >> 16);
}
__device__ __forceinline__ float bf2f(u16 h) {
  return __uint_as_float(((unsigned int)h) << 16);
}
__device__ __forceinline__ u16 f2h(float f) {
  _Float16 h = (_Float16)f;
  return __builtin_bit_cast(unsigned short, h);
}
__device__ __forceinline__ float h2f(u16 b) {
  return (float)__builtin_bit_cast(_Float16, b);
}

// C[M][N] = scale*(A @ Bt^T) (+ beta*C), A/Bt 16-bit row-major [rows][K].
// K = nseg*1024 via segment pointers (A0,A1 / B0,B1); nseg in {1,2}.
// DT: 0=bf16, 1=f16 MFMA. CM: 0=f32 out (beta), 1=bf16 out, 2=f16 hi/lo out (C0,C1).
// Batched over blockIdx.z. 128x128 tile, BK=32, 256 thr = 4 waves (2x2 of 64x64).
template<int DT, int CM>
__global__ __launch_bounds__(256)
void gemm16(const u16* __restrict__ A0, const u16* __restrict__ A1,
            const u16* __restrict__ B0, const u16* __restrict__ B1,
            void* __restrict__ C0, void* __restrict__ C1,
            int M, int N, int nseg, int lda, int ldb,
            long batchA, long batchB, long batchC, float scale, float beta)
{
  __shared__ u16 lA[4096];   // [128][32] bf16/f16, 8 KB (linear byte = t*16 map)
  __shared__ u16 lB[4096];

  const int t    = threadIdx.x;
  const int lane = t & 63;
  const int wave = t >> 6;
  const int wm   = (wave >> 1) << 6;
  const int wn   = (wave & 1) << 6;
  const int bm   = blockIdx.x << 7;
  const int bn   = blockIdx.y << 7;

  A0 += (size_t)blockIdx.z * batchA;  A1 += (size_t)blockIdx.z * batchA;
  B0 += (size_t)blockIdx.z * batchB;  B1 += (size_t)blockIdx.z * batchB;

  // staging map: LDS byte o = t*16 (+4096 for 2nd half) -> row = t>>2 (+64), col=(t&3)*8
  const int sr  = t >> 2;
  const int scc = (t & 3) << 3;
  const size_t aoff0 = (size_t)(bm + sr) * lda + scc;
  const size_t aoff1 = (size_t)(bm + 64 + sr) * lda + scc;
  const size_t boff0 = (size_t)(bn + sr) * ldb + scc;
  const size_t boff1 = (size_t)(bn + 64 + sr) * ldb + scc;
  u16* sA0 = &lA[t << 3];           // byte t*16
  u16* sA1 = &lA[2048 + (t << 3)];
  u16* sB0 = &lB[t << 3];
  u16* sB1 = &lB[2048 + (t << 3)];

  f32x4 acc[4][4];
#pragma unroll
  for (int mi = 0; mi < 4; ++mi)
#pragma unroll
    for (int ni = 0; ni < 4; ++ni)
      acc[mi][ni] = (f32x4){0.f, 0.f, 0.f, 0.f};

  const int kg = lane >> 4;
  const int lr = lane & 15;
  const int NT = nseg << 5;

  // preload K-step 0 into regs
  u16x8 ra0 = *(const u16x8*)(A0 + aoff0);
  u16x8 ra1 = *(const u16x8*)(A0 + aoff1);
  u16x8 rb0 = *(const u16x8*)(B0 + boff0);
  u16x8 rb1 = *(const u16x8*)(B0 + boff1);

  for (int kt = 0; kt < NT; ++kt) {
    __syncthreads();                 // prior frag reads complete before overwrite
    *(u16x8*)sA0 = ra0;
    *(u16x8*)sA1 = ra1;
    *(u16x8*)sB0 = rb0;
    *(u16x8*)sB1 = rb1;
    __syncthreads();                 // tile visible to all waves

    if (kt + 1 < NT) {               // prefetch next tile (overlaps MFMA)
      const u16* As = ((kt + 1) & 32) ? A1 : A0;
      const u16* Bs = ((kt + 1) & 32) ? B1 : B0;
      const int ko = ((kt + 1) & 31) << 5;
      ra0 = *(const u16x8*)(As + aoff0 + ko);
      ra1 = *(const u16x8*)(As + aoff1 + ko);
      rb0 = *(const u16x8*)(Bs + boff0 + ko);
      rb1 = *(const u16x8*)(Bs + boff1 + ko);
    }

    u16x8 fa[4], fb[4];
#pragma unroll
    for (int mi = 0; mi < 4; ++mi)
      fa[mi] = *(const u16x8*)&lA[((wm + (mi << 4) + lr) << 5) + (kg << 3)];
#pragma unroll
    for (int ni = 0; ni < 4; ++ni)
      fb[ni] = *(const u16x8*)&lB[((wn + (ni << 4) + lr) << 5) + (kg << 3)];
#pragma unroll
    for (int mi = 0; mi < 4; ++mi)
#pragma unroll
      for (int ni = 0; ni < 4; ++ni) {
        if constexpr (DT == 0)
          acc[mi][ni] = __builtin_amdgcn_mfma_f32_16x16x32_bf16(
              __builtin_bit_cast(bf16x8, fa[mi]), __builtin_bit_cast(bf16x8, fb[ni]),
              acc[mi][ni], 0, 0, 0);
        else
          acc[mi][ni] = __builtin_amdgcn_mfma_f32_16x16x32_f16(
              __builtin_bit_cast(f16x8, fa[mi]), __builtin_bit_cast(f16x8, fb[ni]),
              acc[mi][ni], 0, 0, 0);
      }
  }

  // D lane map: col=lane&15, row=(lane>>4)*4+i  [m89-verified]
  const size_t cb = (size_t)blockIdx.z * batchC;
#pragma unroll
  for (int mi = 0; mi < 4; ++mi)
#pragma unroll
    for (int ni = 0; ni < 4; ++ni) {
      const int row0 = bm + wm + (mi << 4) + ((lane >> 4) << 2);
      const int col  = bn + wn + (ni << 4) + lr;
#pragma unroll
      for (int i = 0; i < 4; ++i) {
        float v = acc[mi][ni][i] * scale;
        const size_t idx = cb + (size_t)(row0 + i) * N + col;
        if constexpr (CM == 0) {
          float* C = (float*)C0;
          if (beta != 0.f) v += beta * C[idx];
          C[idx] = v;
        } else if constexpr (CM == 1) {
          ((u16*)C0)[idx] = f2bf(v);
        } else {
          u16 hb = f2h(v);
          ((u16*)C0)[idx] = hb;
          ((u16*)C1)[idx] = f2h(v - h2f(hb));
        }
      }
    }
}

// out[c][r] = cvt(in[r*ldin + c + coff]); IM: 0=f32,1=bf16 in; OM: 1=bf16,2=f16 out.
template<int IM, int OM>
__global__ __launch_bounds__(256)
void transpose_cvt(const void* __restrict__ inv, u16* __restrict__ out,
                   int R, int C, int ldin, int coff, long sIn, long sOut)
{
  __shared__ float tile[32][33];
  const int tx = threadIdx.x, ty = threadIdx.y;
  const int c0 = blockIdx.x << 5, r0 = blockIdx.y << 5;
#pragma unroll
  for (int i = 0; i < 4; ++i) {
    int r = ty + (i << 3);
    size_t idx = (size_t)blockIdx.z * sIn + (size_t)(r0 + r) * ldin + c0 + tx + coff;
    float v;
    if constexpr (IM == 0) v = ((const float*)inv)[idx];
    else                   v = bf2f(((const u16*)inv)[idx]);
    tile[r][tx] = v;
  }
  __syncthreads();
#pragma unroll
  for (int i = 0; i < 4; ++i) {
    int r = ty + (i << 3);
    float v = tile[tx][r];
    size_t idx = (size_t)blockIdx.z * sOut + (size_t)(c0 + r) * R + r0 + tx;
    out[idx] = (OM == 1) ? f2bf(v) : f2h(v);
  }
}

__global__ __launch_bounds__(256)
void cvt_bf16k(const float* __restrict__ in, u16* __restrict__ out, int n4)
{
  int i = blockIdx.x * 256 + threadIdx.x;
  const int stride = gridDim.x * 256;
  for (; i < n4; i += stride) {
    float4 f = ((const float4*)in)[i];
    u16x4 o;
    o[0] = f2bf(f.x); o[1] = f2bf(f.y); o[2] = f2bf(f.z); o[3] = f2bf(f.w);
    ((u16x4*)out)[i] = o;
  }
}

// flat softmax over 1M elems/batch: per-4096-chunk (max, sum e^(x-max)).
__global__ __launch_bounds__(256)
void softmax_pass1(const float* __restrict__ sc, float2* __restrict__ part)
{
  const int b = blockIdx.y;
  const float* p = sc + ((size_t)b << 20) + ((size_t)blockIdx.x << 12);
  const int t = threadIdx.x;
  float v[16];
#pragma unroll
  for (int i = 0; i < 4; ++i) {
    float4 f = *(const float4*)(p + (t << 2) + (i << 10));
    v[i * 4 + 0] = f.x; v[i * 4 + 1] = f.y; v[i * 4 + 2] = f.z; v[i * 4 + 3] = f.w;
  }
  float m = v[0];
#pragma unroll
  for (int i = 1; i < 16; ++i) m = fmaxf(m, v[i]);
  for (int off = 32; off; off >>= 1) m = fmaxf(m, __shfl_down(m, off));
  __shared__ float red[8];
  if ((t & 63) == 0) red[t >> 6] = m;
  __syncthreads();
  m = fmaxf(fmaxf(red[0], red[1]), fmaxf(red[2], red[3]));
  float s = 0.f;
#pragma unroll
  for (int i = 0; i < 16; ++i) s += __expf(v[i] - m);
  for (int off = 32; off; off >>= 1) s += __shfl_down(s, off);
  if ((t & 63) == 0) red[4 + (t >> 6)] = s;
  __syncthreads();
  if (t == 0) part[(b << 8) + blockIdx.x] = make_float2(m, red[4] + red[5] + red[6] + red[7]);
}

__global__ __launch_bounds__(256)
void softmax_pass2(const float2* __restrict__ part, float2* __restrict__ bstats)
{
  const int b = blockIdx.x, t = threadIdx.x;
  float2 pr = part[(b << 8) + t];
  float m = pr.x;
  for (int off = 32; off; off >>= 1) m = fmaxf(m, __shfl_down(m, off));
  __shared__ float red[8];
  if ((t & 63) == 0) red[t >> 6] = m;
  __syncthreads();
  m = fmaxf(fmaxf(red[0], red[1]), fmaxf(red[2], red[3]));
  float s = pr.y * __expf(pr.x - m);
  for (int off = 32; off; off >>= 1) s += __shfl_down(s, off);
  __shared__ float red2[4];
  if ((t & 63) == 0) red2[t >> 6] = s;
  __syncthreads();
  if (t == 0) bstats[b] = make_float2(m, 1.f / (red2[0] + red2[1] + red2[2] + red2[3]));
}

__global__ __launch_bounds__(256)
void softmax_pass3(const float* __restrict__ sc, u16* __restrict__ wb,
                   const float2* __restrict__ bst)
{
  const int b = blockIdx.y;
  const float2 st = bst[b];
  const size_t off = ((size_t)b << 20) + ((size_t)blockIdx.x << 12) + ((size_t)threadIdx.x << 2);
  const float* p = sc + off;
  u16* o = wb + off;
#pragma unroll
  for (int i = 0; i < 4; ++i) {
    float4 f = *(const float4*)(p + (i << 10));
    u16x4 u;
    u[0] = f2bf(__expf(f.x - st.x) * st.y);
    u[1] = f2bf(__expf(f.y - st.x) * st.y);
    u[2] = f2bf(__expf(f.z - st.x) * st.y);
    u[3] = f2bf(__expf(f.w - st.x) * st.y);
    *(u16x4*)(o + (i << 10)) = u;
  }
}

// out = LN(a + res) * g + b ; one block per 1024-elem row.
// AM: 0 a=f32, 1 a=bf16.  RM: 0 res=f32 (r0), 1 res=f16 pair (r0+r1).
// OM: 0 out=f32 (o0), 1 out=f16 hi/lo (o0,o1).
template<int AM, int RM, int OM>
__global__ __launch_bounds__(256)
void ln_fused(const void* __restrict__ av, const void* __restrict__ r0v,
              const void* __restrict__ r1v, const float* __restrict__ g,
              const float* __restrict__ bb, void* __restrict__ o0v,
              void* __restrict__ o1v)
{
  const size_t base = (size_t)blockIdx.x << 10;
  const int t = threadIdx.x;
  float x[4];
  if constexpr (AM == 0) {
    float4 a = *(const float4*)((const float*)av + base + (t << 2));
    x[0] = a.x; x[1] = a.y; x[2] = a.z; x[3] = a.w;
  } else {
    u16x4 a = *(const u16x4*)((const u16*)av + base + (t << 2));
#pragma unroll
    for (int i = 0; i < 4; ++i) x[i] = bf2f(a[i]);
  }
  if constexpr (RM == 0) {
    float4 r = *(const float4*)((const float*)r0v + base + (t << 2));
    x[0] += r.x; x[1] += r.y; x[2] += r.z; x[3] += r.w;
  } else {
    u16x4 rh = *(const u16x4*)((const u16*)r0v + base + (t << 2));
    u16x4 rl = *(const u16x4*)((const u16*)r1v + base + (t << 2));
#pragma unroll
    for (int i = 0; i < 4; ++i) x[i] += h2f(rh[i]) + h2f(rl[i]);
  }
  float s = x[0] + x[1] + x[2] + x[3];
  float q = x[0]*x[0] + x[1]*x[1] + x[2]*x[2] + x[3]*x[3];
  for (int off = 32; off; off >>= 1) { s += __shfl_down(s, off); q += __shfl_down(q, off); }
  __shared__ float red[8];
  if ((t & 63) == 0) { red[t >> 6] = s; red[4 + (t >> 6)] = q; }
  __syncthreads();
  float S = red[0] + red[1] + red[2] + red[3];
  float Q = red[4] + red[5] + red[6] + red[7];
  float mu   = S * 0.0009765625f;
  float rstd = rsqrtf(Q * 0.0009765625f - mu * mu + 1e-5f);
  float4 vg = *(const float4*)(g + (t << 2));
  float4 vb = *(const float4*)(bb + (t << 2));
  float y[4];
  y[0] = (x[0] - mu) * rstd * vg.x + vb.x;
  y[1] = (x[1] - mu) * rstd * vg.y + vb.y;
  y[2] = (x[2] - mu) * rstd * vg.z + vb.z;
  y[3] = (x[3] - mu) * rstd * vg.w + vb.w;
  if constexpr (OM == 0) {
    float4 o = {y[0], y[1], y[2], y[3]};
    *(float4*)((float*)o0v + base + (t << 2)) = o;
  } else {
    u16x4 oh, ol;
#pragma unroll
    for (int i = 0; i < 4; ++i) {
      oh[i] = f2h(y[i]);
      ol[i] = f2h(y[i] - h2f(oh[i]));
    }
    *(u16x4*)((u16*)o0v + base + (t << 2)) = oh;
    *(u16x4*)((u16*)o1v + base + (t << 2)) = ol;
  }
}

extern "C" void kernel_launch(void* const* d_in, const int* in_sizes, int n_in,
                              void* d_out, int out_size, void* d_ws, size_t ws_size,
                              hipStream_t stream)
{
  const float* pl  = (const float*)d_in[0];
  const float* sam = (const float*)d_in[1];
  const float* Wq  = (const float*)d_in[2];
  const float* Wk  = (const float*)d_in[3];
  const float* Wv  = (const float*)d_in[4];
  const float* g1  = (const float*)d_in[5];
  const float* b1  = (const float*)d_in[6];
  const float* W1  = (const float*)d_in[7];
  const float* W2  = (const float*)d_in[8];
  const float* g2  = (const float*)d_in[9];
  const float* b2  = (const float*)d_in[10];

  // ---- workspace (206.3 MiB peak, regions reused; liveness verified) ----
  char* wsb = (char*)d_ws;
  const size_t MB = 1ull << 20;
  u16*   plb   = (u16*)(wsb + 0 * MB);     // -> sc[0:32) -> hhH
  u16*   samb  = (u16*)(wsb + 32 * MB);    // -> sc[32:64) -> hlH
  u16*   qb    = (u16*)(wsb + 64 * MB);    // -> wb -> xh
  u16*   vTb   = (u16*)(wsb + 96 * MB);    // -> xl
  u16*   kvb   = (u16*)(wsb + 128 * MB);   // 64 MiB -> attnb(first half) -> ff
  float* sc    = (float*)(wsb + 0 * MB);
  u16*   wb    = qb;
  u16*   attnb = kvb;
  u16*   xh    = qb;
  u16*   xl    = vTb;
  u16*   hhH   = (u16*)(wsb + 0 * MB);
  u16*   hlH   = (u16*)(wsb + 32 * MB);
  float* ff    = (float*)(wsb + 128 * MB);
  u16*   WqTb  = (u16*)(wsb + 192 * MB);   // bf16 [1024][1024]
  u16*   WkvTb = (u16*)(wsb + 194 * MB);   // bf16 [2048][1024]
  u16*   W1Th  = (u16*)(wsb + 198 * MB);   // f16  [2048][1024]
  u16*   W2Th  = (u16*)(wsb + 202 * MB);   // f16  [1024][2048]
  float2* part = (float2*)(wsb + 206 * MB);
  float2* bst  = (float2*)(wsb + 206 * MB + 65536);

  const long M1 = 1 << 20, M2 = 2 << 20;
  dim3 tb(32, 8);

  // input/weight prep
  cvt_bf16k<<<2048, 256, 0, stream>>>(pl,  plb,  1 << 22);
  cvt_bf16k<<<2048, 256, 0, stream>>>(sam, samb, 1 << 22);
  transpose_cvt<0,1><<<dim3(32, 32, 1), tb, 0, stream>>>(Wq, WqTb, 1024, 1024, 1024, 0, 0, 0);
  transpose_cvt<0,1><<<dim3(32, 32, 1), tb, 0, stream>>>(Wk, WkvTb, 1024, 1024, 1024, 0, 0, 0);
  transpose_cvt<0,1><<<dim3(32, 32, 1), tb, 0, stream>>>(Wv, WkvTb + M1, 1024, 1024, 1024, 0, 0, 0);
  transpose_cvt<0,2><<<dim3(64, 32, 1), tb, 0, stream>>>(W1, W1Th, 1024, 2048, 2048, 0, 0, 0);
  transpose_cvt<0,2><<<dim3(32, 64, 1), tb, 0, stream>>>(W2, W2Th, 2048, 1024, 1024, 0, 0, 0);

  // projections: q = plb@WqT (bf16 out); kv = samb@[WkT;WvT] (N=2048)
  gemm16<0,1><<<dim3(128, 8, 1), 256, 0, stream>>>(plb, plb, WqTb, WqTb, qb, nullptr,
      16384, 1024, 1, 1024, 1024, 0, 0, 0, 1.f, 0.f);
  gemm16<0,1><<<dim3(128, 16, 1), 256, 0, stream>>>(samb, samb, WkvTb, WkvTb, kvb, nullptr,
      16384, 2048, 1, 1024, 1024, 0, 0, 0, 1.f, 0.f);

  // vT = v^T per batch (v = kvb cols 1024:2048)
  transpose_cvt<1,1><<<dim3(32, 32, 16), tb, 0, stream>>>(kvb, vTb, 1024, 1024, 2048, 1024, M2, M1);

  // scores = q @ k^T / 32 (k = kvb cols 0:1024, ldb=2048)
  gemm16<0,0><<<dim3(8, 8, 16), 256, 0, stream>>>(qb, qb, kvb, kvb, sc, nullptr,
      1024, 1024, 1, 1024, 2048, M1, M2, M1, 0.03125f, 0.f);

  softmax_pass1<<<dim3(256, 16, 1), 256, 0, stream>>>(sc, part);
  softmax_pass2<<<16, 256, 0, stream>>>(part, bst);
  softmax_pass3<<<dim3(256, 16, 1), 256, 0, stream>>>(sc, wb, bst);

  // attn = w @ v (B^T = vT), bf16 out
  gemm16<0,1><<<dim3(8, 8, 16), 256, 0, stream>>>(wb, wb, vTb, vTb, attnb, nullptr,
      1024, 1024, 1, 1024, 1024, M1, M1, M1, 1.f, 0.f);

  // x = LN1(attn + pl) -> fp16 hi/lo
  ln_fused<1,0,1><<<16384, 256, 0, stream>>>(attnb, pl, nullptr, g1, b1, xh, xl);

  // FFN in fp16 2-term split, N-halved (h) / K-halved (ff accumulate)
  // h_half = [xh|xl] @ [W1h|W1h]^T  (K=2048) -> fp16 hi/lo
  // ff (+)= [hh|hl] @ [W2h|W2h]^T  (K=2048)
  gemm16<1,2><<<dim3(128, 8, 1), 256, 0, stream>>>(xh, xl, W1Th, W1Th, hhH, hlH,
      16384, 1024, 2, 1024, 1024, 0, 0, 0, 1.f, 0.f);
  gemm16<1,0><<<dim3(128, 8, 1), 256, 0, stream>>>(hhH, hlH, W2Th, W2Th, ff, nullptr,
      16384, 1024, 2, 1024, 2048, 0, 0, 0, 1.f, 0.f);
  gemm16<1,2><<<dim3(128, 8, 1), 256, 0, stream>>>(xh, xl, W1Th + M1, W1Th + M1, hhH, hlH,
      16384, 1024, 2, 1024, 1024, 0, 0, 0, 1.f, 0.f);
  gemm16<1,0><<<dim3(128, 8, 1), 256, 0, stream>>>(hhH, hlH, W2Th + 1024, W2Th + 1024, ff, nullptr,
      16384, 1024, 2, 1024, 2048, 0, 0, 0, 1.f, 1.f);

  // out = LN2(ff + x)
  ln_fused<0,1,0><<<16384, 256, 0, stream>>>(ff, xh, xl, g2, b2, d_out, nullptr);
}